// Round 7
// baseline (63.326 us; speedup 1.0000x reference)
//
#include <hip/hip_runtime.h>

// Problem constants (match reference)
#define PP 32   // patches
#define SS 4
#define CC 64
#define HH 128
#define WW 128
#define NC 32   // channels kept per patch
#define OO 32   // adaptive pool output size (MIN_SIZE)
#define PLANE (HH * WW)

// ws: int pbase[PP*NC]; int psize[PP]; int poffx[PP]
// pbase[p*NC+c] = element offset of (p, s=0, channels[p][c]) plane + offy rows
// (NO offx — phase 1 reads full 512B rows; offx applied in phase 2).
__global__ __launch_bounds__(256) void setup_kernel(
    const int* __restrict__ size_raw,
    const int* __restrict__ pix,
    const int* __restrict__ channels,
    int*       __restrict__ pbase,   // [PP*NC]
    int*       __restrict__ psize,   // [PP]
    int*       __restrict__ poffx)   // [PP]
{
    const int i = blockIdx.x * 256 + threadIdx.x;   // 0..1023
    const int p = i >> 5;
    const int c = i & 31;
    const int size = size_raw[p] + OO;              // [32,128]
    const int wr = WW - size + 1;
    const int hr = HH - size + 1;
    const int pm = pix[p] % (wr * hr);
    const int offy = pm / wr;
    const int offx = pm - offy * wr;
    if (c == 0) { psize[p] = size; poffx[p] = offx; }
    const int ch = channels[p * NC + c];
    pbase[i] = (p * SS * CC + ch) * PLANE + offy * WW;
}

// One 256-thread block per (p,s,c) crop.
// Phase 1: halves (128 lanes) own 16 o-bins each; lane x sweeps the bin's
//          rows reading FULL plane rows (column x, x=0..127) -> each block's
//          DRAM footprint is one contiguous size*512B chunk, streamed once
//          (bin-boundary overlap rows are L1 hits). Column sums in LDS.
// Phase 2: one barrier; each thread produces 4 consecutive q outputs from
//          the column sums at offx+.., one contiguous float4 store.
__global__ __launch_bounds__(256) void pool_kernel(
    const float* __restrict__ input,   // [P,S,C,H,W]
    const int*   __restrict__ pbase,   // [PP*NC]
    const int*   __restrict__ psize,   // [PP]
    const int*   __restrict__ poffx,   // [PP]
    float*       __restrict__ out)     // [P,S,NC,O,O]
{
    __shared__ float cs[OO][129];

    const int blk = blockIdx.x;        // (p<<7)|(s<<5)|c
    const int c = blk & (NC - 1);
    const int s = (blk >> 5) & (SS - 1);
    const int p = blk >> 7;
    const int t = threadIdx.x;
    const int x = t & 127;             // full-plane column owned by this lane
    const int h = t >> 7;              // o-half (0: o<16, 1: o>=16)

    const int size = psize[p];         // wave-uniform
    const int offx = poffx[p];
    const float* base = input + pbase[(p << 5) | c] + s * (CC * PLANE);

    const int o0 = h << 4;
    for (int oi = 0; oi < 16; ++oi) {
        const int o  = o0 + oi;
        const int sy = (o * size) >> 5;
        const int ey = ((o + 1) * size + 31) >> 5;
        float a = 0.0f;
        const float* r = base + sy * WW + x;
        for (int y = sy; y < ey; ++y, r += WW) a += *r;
        cs[o][x] = a;                  // stride-1 across lanes: conflict-free
    }
    __syncthreads();

    // Phase 2: outputs i0..i0+3 of this block's 32x32 tile
    const int i0 = t << 2;
    const int q0 = i0 & (OO - 1);
    const int o  = i0 >> 5;
    const int rows = (((o + 1) * size + 31) >> 5) - ((o * size) >> 5);

    float acc[4];
    #pragma unroll
    for (int j = 0; j < 4; ++j) {
        const int q  = q0 + j;
        const int sx = (q * size) >> 5;
        const int ex = ((q + 1) * size + 31) >> 5;
        float a = 0.0f;
        for (int xx = sx; xx < ex; ++xx) a += cs[o][offx + xx];
        acc[j] = a * __builtin_amdgcn_rcpf((float)(rows * (ex - sx)));
    }
    *(float4*)(out + ((size_t)blk << 10) + i0) =
        make_float4(acc[0], acc[1], acc[2], acc[3]);
}

extern "C" void kernel_launch(void* const* d_in, const int* in_sizes, int n_in,
                              void* d_out, int out_size, void* d_ws, size_t ws_size,
                              hipStream_t stream) {
    const float* input    = (const float*)d_in[0];
    const int*   size_raw = (const int*)d_in[1];
    const int*   pix      = (const int*)d_in[2];
    const int*   channels = (const int*)d_in[3];
    float*       out      = (float*)d_out;

    int* pbase = (int*)d_ws;            // 1024 ints
    int* psize = pbase + PP * NC;       // 32 ints
    int* poffx = psize + PP;            // 32 ints

    setup_kernel<<<4, 256, 0, stream>>>(size_raw, pix, channels, pbase, psize, poffx);

    const int grid = PP * SS * NC;      // 4096 blocks
    pool_kernel<<<grid, 256, 0, stream>>>(input, pbase, psize, poffx, out);
}